// Round 8
// baseline (277.414 us; speedup 1.0000x reference)
//
#include <hip/hip_runtime.h>

#define L_LM 2000
#define F_DIM 64
#define B_SZ 2048

#define SPAN_L 16                  // landmarks per wave-span (4 KB out)
#define SPANS_PER_ROW 125          // 2000/16
#define SPAN_F4 256                // 16*64/4 float4 per span
#define DGRID 2000                 // delta blocks (x256 thr = 8000 waves)
#define WAVES_TOT (DGRID * 4)
#define DK 32                      // 256000 spans / 8000 waves

typedef float f32x4 __attribute__((ext_vector_type(4)));

// ---------------- Kernel 1: BMU (argmin of squared distance) ----------------
__global__ __launch_bounds__(256) void som_bmu_kernel(
    const float* __restrict__ x, const float* __restrict__ lm,
    int* __restrict__ min_idx)
{
    constexpr int ROWS = 8;
    const int b0 = blockIdx.x * ROWS;
    const int tid = threadIdx.x;

    __shared__ float xs[ROWS][F_DIM];
    for (int i = tid; i < ROWS * F_DIM; i += 256) {
        xs[i / F_DIM][i % F_DIM] = x[(size_t)(b0 + i / F_DIM) * F_DIM + (i % F_DIM)];
    }
    __syncthreads();

    float best[ROWS];
    int   bidx[ROWS];
#pragma unroll
    for (int r = 0; r < ROWS; ++r) { best[r] = 3.4e38f; bidx[r] = 0; }

    for (int l = tid; l < L_LM; l += 256) {
        const float4* lp = reinterpret_cast<const float4*>(lm + (size_t)l * F_DIM);
        float dot[ROWS];
        float l2 = 0.f;
#pragma unroll
        for (int r = 0; r < ROWS; ++r) dot[r] = 0.f;
#pragma unroll
        for (int k = 0; k < F_DIM / 4; ++k) {
            float4 v = lp[k];
            l2 += v.x * v.x + v.y * v.y + v.z * v.z + v.w * v.w;
#pragma unroll
            for (int r = 0; r < ROWS; ++r) {
                dot[r] += v.x * xs[r][4 * k + 0] + v.y * xs[r][4 * k + 1]
                        + v.z * xs[r][4 * k + 2] + v.w * xs[r][4 * k + 3];
            }
        }
#pragma unroll
        for (int r = 0; r < ROWS; ++r) {
            float s = l2 - 2.f * dot[r];
            if (s < best[r]) { best[r] = s; bidx[r] = l; }
        }
    }

#pragma unroll
    for (int r = 0; r < ROWS; ++r) {
        float s = best[r]; int i = bidx[r];
        for (int off = 32; off > 0; off >>= 1) {
            float s2 = __shfl_down(s, off);
            int   i2 = __shfl_down(i, off);
            if (s2 < s || (s2 == s && i2 < i)) { s = s2; i = i2; }
        }
        best[r] = s; bidx[r] = i;
    }

    __shared__ float sbest[4][ROWS];
    __shared__ int   sidx[4][ROWS];
    const int wave = tid >> 6;
    const int lane = tid & 63;
    if (lane == 0) {
#pragma unroll
        for (int r = 0; r < ROWS; ++r) { sbest[wave][r] = best[r]; sidx[wave][r] = bidx[r]; }
    }
    __syncthreads();
    if (tid < ROWS) {
        float s = sbest[0][tid]; int i = sidx[0][tid];
#pragma unroll
        for (int w = 1; w < 4; ++w) {
            float s2 = sbest[w][tid]; int i2 = sidx[w][tid];
            if (s2 < s || (s2 == s && i2 < i)) { s = s2; i = i2; }
        }
        min_idx[b0 + tid] = i;
    }
}

// ---------------- Kernel 1c: h precompute (hs[b][l] = qd[min_idx[b]][l]) ---
__global__ __launch_bounds__(256) void som_h_kernel(
    const float* __restrict__ qd, const int* __restrict__ min_idx,
    f32x4* __restrict__ hs4)
{
    constexpr unsigned NH4 = (unsigned)B_SZ * (L_LM / 4);
    constexpr unsigned RH4 = L_LM / 4;
    const f32x4* __restrict__ qd4 = reinterpret_cast<const f32x4*>(qd);
    const unsigned stride = gridDim.x * 256u;
    for (unsigned i = blockIdx.x * 256u + threadIdx.x; i < NH4; i += stride) {
        const unsigned b = i / RH4;
        const unsigned c = i - b * RH4;
        hs4[i] = qd4[(unsigned)min_idx[b] * RH4 + c];
    }
}

// ---------------- Kernel 2: delta0 — wave-span, barrier-free, counted vmcnt -
// Each WAVE owns a 16-landmark span (4 KB contiguous out); 8000 resident
// waves grid-stride spans so the live write window is one contiguous ~32 MB
// slide (fill-like). All inputs for span k+1 are prefetched to REGISTERS
// before span k's stores are issued: the in-order vmcnt FIFO is then
// [loads_k | stores_{k-1} | loads_{k+1}], so waiting for loads_k leaves
// stores outstanding (counted vmcnt, never a drain). No LDS, no barriers.
// Explicit even/odd register double-buffer keeps all indexing static.
// lm (512 KB) stays L2-hot under the window; nt stores avoid evicting it.
__global__ __launch_bounds__(256) void som_delta_kernel(
    const float* __restrict__ x, const float* __restrict__ lm,
    const float* __restrict__ hs, f32x4* __restrict__ out)
{
    const int lane = threadIdx.x & 63;
    const int gw   = (blockIdx.x << 2) | (threadIdx.x >> 6);  // 0..7999
    const unsigned s4 = (unsigned)(lane >> 4);
    const unsigned f4 = (unsigned)(lane & 15);
    const f32x4* __restrict__ lm4 = reinterpret_cast<const f32x4*>(lm);
    const f32x4* __restrict__ x4  = reinterpret_cast<const f32x4*>(x);

#define PREFETCH(SP, L0, L1, L2, L3, H0, H1, H2, H3, XV)                  \
    {                                                                     \
        const unsigned bb_ = (SP) / (unsigned)SPANS_PER_ROW;              \
        const unsigned sr_ = (SP) - bb_ * (unsigned)SPANS_PER_ROW;        \
        const f32x4* lp_ = lm4 + sr_ * (unsigned)SPAN_F4;                 \
        L0 = lp_[lane];        L1 = lp_[64 + lane];                       \
        L2 = lp_[128 + lane];  L3 = lp_[192 + lane];                      \
        const float* hp_ = hs + bb_ * (unsigned)L_LM + sr_ * 16u + s4;    \
        H0 = hp_[0]; H1 = hp_[4]; H2 = hp_[8]; H3 = hp_[12];              \
        XV = x4[(bb_ << 4) | f4];                                         \
    }

#define STORESPAN(SP, L0, L1, L2, L3, H0, H1, H2, H3, XV)                 \
    {                                                                     \
        f32x4* ob_ = out + (size_t)(SP) * SPAN_F4 + lane;                 \
        f32x4 o_;                                                         \
        o_.x = H0 * (XV.x - L0.x); o_.y = H0 * (XV.y - L0.y);             \
        o_.z = H0 * (XV.z - L0.z); o_.w = H0 * (XV.w - L0.w);             \
        __builtin_nontemporal_store(o_, &ob_[0]);                         \
        o_.x = H1 * (XV.x - L1.x); o_.y = H1 * (XV.y - L1.y);             \
        o_.z = H1 * (XV.z - L1.z); o_.w = H1 * (XV.w - L1.w);             \
        __builtin_nontemporal_store(o_, &ob_[64]);                        \
        o_.x = H2 * (XV.x - L2.x); o_.y = H2 * (XV.y - L2.y);             \
        o_.z = H2 * (XV.z - L2.z); o_.w = H2 * (XV.w - L2.w);             \
        __builtin_nontemporal_store(o_, &ob_[128]);                       \
        o_.x = H3 * (XV.x - L3.x); o_.y = H3 * (XV.y - L3.y);             \
        o_.z = H3 * (XV.z - L3.z); o_.w = H3 * (XV.w - L3.w);             \
        __builtin_nontemporal_store(o_, &ob_[192]);                       \
    }

    f32x4 a0, a1, a2, a3, xa;  float ha0, ha1, ha2, ha3;
    f32x4 c0, c1, c2, c3, xc;  float hc0, hc1, hc2, hc3;

    unsigned span = (unsigned)gw;
    PREFETCH(span, a0, a1, a2, a3, ha0, ha1, ha2, ha3, xa);

    for (int k = 0; k < DK; k += 2) {
        const unsigned sp1 = span + WAVES_TOT;                  // k+1 (<DK always)
        const unsigned sp2 = (k + 2 < DK) ? sp1 + WAVES_TOT : sp1;
        PREFETCH(sp1, c0, c1, c2, c3, hc0, hc1, hc2, hc3, xc);
        STORESPAN(span, a0, a1, a2, a3, ha0, ha1, ha2, ha3, xa);
        PREFETCH(sp2, a0, a1, a2, a3, ha0, ha1, ha2, ha3, xa);
        STORESPAN(sp1, c0, c1, c2, c3, hc0, hc1, hc2, hc3, xc);
        span = sp2;
    }
#undef PREFETCH
#undef STORESPAN
}

extern "C" void kernel_launch(void* const* d_in, const int* in_sizes, int n_in,
                              void* d_out, int out_size, void* d_ws, size_t ws_size,
                              hipStream_t stream) {
    const float* x  = (const float*)d_in[0];
    const float* lm = (const float*)d_in[1];
    const float* qd = (const float*)d_in[2];
    float* out = (float*)d_out;

    int*   midx = (int*)d_ws;
    float* hs   = (float*)((char*)d_ws + (1u << 20));

    som_bmu_kernel<<<B_SZ / 8, 256, 0, stream>>>(x, lm, midx);
    som_h_kernel<<<1024, 256, 0, stream>>>(qd, midx, (f32x4*)hs);
    som_delta_kernel<<<DGRID, 256, 0, stream>>>(x, lm, hs, (f32x4*)out);
}

// Round 9
// 269.183 us; speedup vs baseline: 1.0306x; 1.0306x over previous
//
#include <hip/hip_runtime.h>

#define L_LM 2000
#define F_DIM 64
#define B_SZ 2048

#define SPAN_L 16                  // landmarks per wave-span (4 KB out)
#define SPANS_PER_ROW 125          // 2000/16
#define SPAN_F4 256                // 16*64/4 float4 per span
#define DGRID 250                  // delta blocks (x256 thr = 1000 waves, ~fill occupancy)
#define WAVES_TOT (DGRID * 4)      // 1000
#define DK 256                     // 256000 spans / 1000 waves

typedef float f32x4 __attribute__((ext_vector_type(4)));

// ---------------- Kernel 1: BMU (argmin of squared distance) ----------------
__global__ __launch_bounds__(256) void som_bmu_kernel(
    const float* __restrict__ x, const float* __restrict__ lm,
    int* __restrict__ min_idx)
{
    constexpr int ROWS = 8;
    const int b0 = blockIdx.x * ROWS;
    const int tid = threadIdx.x;

    __shared__ float xs[ROWS][F_DIM];
    for (int i = tid; i < ROWS * F_DIM; i += 256) {
        xs[i / F_DIM][i % F_DIM] = x[(size_t)(b0 + i / F_DIM) * F_DIM + (i % F_DIM)];
    }
    __syncthreads();

    float best[ROWS];
    int   bidx[ROWS];
#pragma unroll
    for (int r = 0; r < ROWS; ++r) { best[r] = 3.4e38f; bidx[r] = 0; }

    for (int l = tid; l < L_LM; l += 256) {
        const float4* lp = reinterpret_cast<const float4*>(lm + (size_t)l * F_DIM);
        float dot[ROWS];
        float l2 = 0.f;
#pragma unroll
        for (int r = 0; r < ROWS; ++r) dot[r] = 0.f;
#pragma unroll
        for (int k = 0; k < F_DIM / 4; ++k) {
            float4 v = lp[k];
            l2 += v.x * v.x + v.y * v.y + v.z * v.z + v.w * v.w;
#pragma unroll
            for (int r = 0; r < ROWS; ++r) {
                dot[r] += v.x * xs[r][4 * k + 0] + v.y * xs[r][4 * k + 1]
                        + v.z * xs[r][4 * k + 2] + v.w * xs[r][4 * k + 3];
            }
        }
#pragma unroll
        for (int r = 0; r < ROWS; ++r) {
            float s = l2 - 2.f * dot[r];
            if (s < best[r]) { best[r] = s; bidx[r] = l; }
        }
    }

#pragma unroll
    for (int r = 0; r < ROWS; ++r) {
        float s = best[r]; int i = bidx[r];
        for (int off = 32; off > 0; off >>= 1) {
            float s2 = __shfl_down(s, off);
            int   i2 = __shfl_down(i, off);
            if (s2 < s || (s2 == s && i2 < i)) { s = s2; i = i2; }
        }
        best[r] = s; bidx[r] = i;
    }

    __shared__ float sbest[4][ROWS];
    __shared__ int   sidx[4][ROWS];
    const int wave = tid >> 6;
    const int lane = tid & 63;
    if (lane == 0) {
#pragma unroll
        for (int r = 0; r < ROWS; ++r) { sbest[wave][r] = best[r]; sidx[wave][r] = bidx[r]; }
    }
    __syncthreads();
    if (tid < ROWS) {
        float s = sbest[0][tid]; int i = sidx[0][tid];
#pragma unroll
        for (int w = 1; w < 4; ++w) {
            float s2 = sbest[w][tid]; int i2 = sidx[w][tid];
            if (s2 < s || (s2 == s && i2 < i)) { s = s2; i = i2; }
        }
        min_idx[b0 + tid] = i;
    }
}

// ---------------- Kernel 1c: h precompute (hs[b][l] = qd[min_idx[b]][l]) ---
__global__ __launch_bounds__(256) void som_h_kernel(
    const float* __restrict__ qd, const int* __restrict__ min_idx,
    f32x4* __restrict__ hs4)
{
    constexpr unsigned NH4 = (unsigned)B_SZ * (L_LM / 4);
    constexpr unsigned RH4 = L_LM / 4;
    const f32x4* __restrict__ qd4 = reinterpret_cast<const f32x4*>(qd);
    const unsigned stride = gridDim.x * 256u;
    for (unsigned i = blockIdx.x * 256u + threadIdx.x; i < NH4; i += stride) {
        const unsigned b = i / RH4;
        const unsigned c = i - b * RH4;
        hs4[i] = qd4[(unsigned)min_idx[b] * RH4 + c];
    }
}

// ---------------- Kernel 2: delta0 — LOW-WAVE-COUNT fill clone --------------
// Single-variable A/B vs R8: grid 2000 -> 250 blocks (1000 waves, matching
// the 6.8 TB/s rocclr fill's ~11% occupancy). All R8 machinery unchanged:
// wave-owned 4 KB spans, register prefetch 1-ahead (counted vmcnt — loads
// for span k+1 issued before span k's stores, never draining the store
// queue), nt stores, no LDS/barriers. At step k the 1000 waves write spans
// [k*1000,(k+1)*1000) = one contiguous 4 MB window sliding through the
// output — the hypothesis is that ~1000 write streams (not 8000) is what
// preserves DRAM row-buffer locality. Issue slack at 1 wave/SIMD is >10x
// what 6.8 TB/s requires; store backpressure remains the governor.
__global__ __launch_bounds__(256) void som_delta_kernel(
    const float* __restrict__ x, const float* __restrict__ lm,
    const float* __restrict__ hs, f32x4* __restrict__ out)
{
    const int lane = threadIdx.x & 63;
    const int gw   = (blockIdx.x << 2) | (threadIdx.x >> 6);  // 0..999
    const unsigned s4 = (unsigned)(lane >> 4);
    const unsigned f4 = (unsigned)(lane & 15);
    const f32x4* __restrict__ lm4 = reinterpret_cast<const f32x4*>(lm);
    const f32x4* __restrict__ x4  = reinterpret_cast<const f32x4*>(x);

#define PREFETCH(SP, L0, L1, L2, L3, H0, H1, H2, H3, XV)                  \
    {                                                                     \
        const unsigned bb_ = (SP) / (unsigned)SPANS_PER_ROW;              \
        const unsigned sr_ = (SP) - bb_ * (unsigned)SPANS_PER_ROW;        \
        const f32x4* lp_ = lm4 + sr_ * (unsigned)SPAN_F4;                 \
        L0 = lp_[lane];        L1 = lp_[64 + lane];                       \
        L2 = lp_[128 + lane];  L3 = lp_[192 + lane];                      \
        const float* hp_ = hs + bb_ * (unsigned)L_LM + sr_ * 16u + s4;    \
        H0 = hp_[0]; H1 = hp_[4]; H2 = hp_[8]; H3 = hp_[12];              \
        XV = x4[(bb_ << 4) | f4];                                         \
    }

#define STORESPAN(SP, L0, L1, L2, L3, H0, H1, H2, H3, XV)                 \
    {                                                                     \
        f32x4* ob_ = out + (size_t)(SP) * SPAN_F4 + lane;                 \
        f32x4 o_;                                                         \
        o_.x = H0 * (XV.x - L0.x); o_.y = H0 * (XV.y - L0.y);             \
        o_.z = H0 * (XV.z - L0.z); o_.w = H0 * (XV.w - L0.w);             \
        __builtin_nontemporal_store(o_, &ob_[0]);                         \
        o_.x = H1 * (XV.x - L1.x); o_.y = H1 * (XV.y - L1.y);             \
        o_.z = H1 * (XV.z - L1.z); o_.w = H1 * (XV.w - L1.w);             \
        __builtin_nontemporal_store(o_, &ob_[64]);                        \
        o_.x = H2 * (XV.x - L2.x); o_.y = H2 * (XV.y - L2.y);             \
        o_.z = H2 * (XV.z - L2.z); o_.w = H2 * (XV.w - L2.w);             \
        __builtin_nontemporal_store(o_, &ob_[128]);                       \
        o_.x = H3 * (XV.x - L3.x); o_.y = H3 * (XV.y - L3.y);             \
        o_.z = H3 * (XV.z - L3.z); o_.w = H3 * (XV.w - L3.w);             \
        __builtin_nontemporal_store(o_, &ob_[192]);                       \
    }

    f32x4 a0, a1, a2, a3, xa;  float ha0, ha1, ha2, ha3;
    f32x4 c0, c1, c2, c3, xc;  float hc0, hc1, hc2, hc3;

    unsigned span = (unsigned)gw;
    PREFETCH(span, a0, a1, a2, a3, ha0, ha1, ha2, ha3, xa);

    for (int k = 0; k < DK; k += 2) {
        const unsigned sp1 = span + WAVES_TOT;                  // k+1 (<DK always)
        const unsigned sp2 = (k + 2 < DK) ? sp1 + WAVES_TOT : sp1;
        PREFETCH(sp1, c0, c1, c2, c3, hc0, hc1, hc2, hc3, xc);
        STORESPAN(span, a0, a1, a2, a3, ha0, ha1, ha2, ha3, xa);
        PREFETCH(sp2, a0, a1, a2, a3, ha0, ha1, ha2, ha3, xa);
        STORESPAN(sp1, c0, c1, c2, c3, hc0, hc1, hc2, hc3, xc);
        span = sp2;
    }
#undef PREFETCH
#undef STORESPAN
}

extern "C" void kernel_launch(void* const* d_in, const int* in_sizes, int n_in,
                              void* d_out, int out_size, void* d_ws, size_t ws_size,
                              hipStream_t stream) {
    const float* x  = (const float*)d_in[0];
    const float* lm = (const float*)d_in[1];
    const float* qd = (const float*)d_in[2];
    float* out = (float*)d_out;

    int*   midx = (int*)d_ws;
    float* hs   = (float*)((char*)d_ws + (1u << 20));

    som_bmu_kernel<<<B_SZ / 8, 256, 0, stream>>>(x, lm, midx);
    som_h_kernel<<<1024, 256, 0, stream>>>(qd, midx, (f32x4*)hs);
    som_delta_kernel<<<DGRID, 256, 0, stream>>>(x, lm, hs, (f32x4*)out);
}